// Round 9
// baseline (525.719 us; speedup 1.0000x reference)
//
#include <hip/hip_runtime.h>
#include <hip/hip_cooperative_groups.h>
#include <math.h>

namespace cg = cooperative_groups;

// GraphAttnModel: N=50000, E=800000, F=256, H=4, D=64.
// Pipeline:
//   1) prep: convert feat+weights+biases to bf16 ws copies, fold gate weights
//      (wgs=Wa+Wc, wgr=Wb-Wc), zero CSR counters
//   2) csr_kernel (COOPERATIVE, one launch): count (per-edge rank via atomic
//      return) -> grid.sync -> alloc (scan-free wave atomics) -> grid.sync ->
//      fill (atomic-free: pos = start[dst]+rank). counts/start stay L2-hot.
//   3) fused bf16 MFMA GEMM (128x256 tile, global_load_lds staging).
//      XCD-co-located grid: the 4 ysel blocks of one mtile map to the SAME
//      XCD (p&7) so the shared featb A-tile is an L2 hit, not 4x L3.
//      q,v outputs stored FP8 e4m3 INTERLEAVED per node (512B row: q|v);
//      k,skip stored bf16.
//   4) one wave per dst node (static): 8 feats/lane, two 32-lane halves,
//      4 chains -> 8 edges / 8 dwordx2 gathers in flight. No-max softmax
//      (logits tiny; shift-invariant) + gate + LayerNorm + PReLU, f32 out.

typedef __attribute__((ext_vector_type(8))) short short8;   // 8 bf16 = 4 VGPRs
typedef __attribute__((ext_vector_type(4))) float floatx4;  // MFMA acc
typedef __attribute__((ext_vector_type(2))) float floatx2;  // fp8 decode pair
typedef __attribute__((address_space(3))) void lds_void;
typedef __attribute__((address_space(1))) const void gbl_void;

__device__ inline unsigned short f2bf(float x) {            // RNE f32->bf16
    unsigned int u = __float_as_uint(x);
    u = (u + 0x7fffu + ((u >> 16) & 1u)) >> 16;
    return (unsigned short)u;
}
__device__ inline float bf2f(unsigned short u) {
    return __uint_as_float(((unsigned int)u) << 16);
}

// ---------------- prep: converts + gate-fold + CSR zero ----------------
__global__ void prep_kernel(const float* __restrict__ f, ushort* __restrict__ fb,
                            int n_elems, int total_pad,
                            const float* __restrict__ Wq, const float* __restrict__ Wk,
                            const float* __restrict__ Wv, const float* __restrict__ Wsk,
                            const float* __restrict__ bq, const float* __restrict__ bk,
                            const float* __restrict__ bv, const float* __restrict__ bsk,
                            const float* __restrict__ Wg,
                            ushort* __restrict__ Wcat, float* __restrict__ bcat,
                            float* __restrict__ wgs, float* __restrict__ wgr,
                            int* __restrict__ counts, int* __restrict__ cursor, int n)
{
    int g = blockIdx.x * blockDim.x + threadIdx.x;
    int featQ = total_pad >> 2;               // feat quads
    if (g < featQ) {
        int i = g * 4;
        float4 v = (i < n_elems) ? *(const float4*)(f + i) : make_float4(0.f, 0.f, 0.f, 0.f);
        ushort4 u;
        u.x = f2bf(v.x); u.y = f2bf(v.y); u.z = f2bf(v.z); u.w = f2bf(v.w);
        *(ushort4*)(fb + i) = u;
        return;
    }
    int g2 = g - featQ;
    if (g2 < 65536) {                         // weights: 262144/4
        int i = g2 * 4;
        int mat = i >> 16;
        int rem = i & 65535;
        const float* W = (mat == 0) ? Wq : (mat == 1) ? Wk : (mat == 2) ? Wv : Wsk;
        float4 v = *(const float4*)(W + rem);
        ushort4 u;
        u.x = f2bf(v.x); u.y = f2bf(v.y); u.z = f2bf(v.z); u.w = f2bf(v.w);
        *(ushort4*)(Wcat + i) = u;
        return;
    }
    int g3 = g2 - 65536;
    if (g3 < 256) {                           // biases: 1024/4
        int o = g3 * 4;
        int mat = o >> 8;
        const float* b = (mat == 0) ? bq : (mat == 1) ? bk : (mat == 2) ? bv : bsk;
        *(float4*)(bcat + o) = *(const float4*)(b + (o & 255));
        return;
    }
    int g4 = g3 - 256;
    if (g4 < 64) {                            // wgs = Wg[0:256] + Wg[512:768]
        int o = g4 * 4;
        float4 a = *(const float4*)(Wg + o);
        float4 c = *(const float4*)(Wg + 512 + o);
        *(float4*)(wgs + o) = make_float4(a.x + c.x, a.y + c.y, a.z + c.z, a.w + c.w);
        return;
    }
    if (g4 < 128) {                           // wgr = Wg[256:512] - Wg[512:768]
        int o = (g4 - 64) * 4;
        float4 b = *(const float4*)(Wg + 256 + o);
        float4 c = *(const float4*)(Wg + 512 + o);
        *(float4*)(wgr + o) = make_float4(b.x - c.x, b.y - c.y, b.z - c.z, b.w - c.w);
        return;
    }
    int g5 = g4 - 128;
    if (g5 < n) counts[g5] = 0;
    if (g5 == 0) *cursor = 0;
}

// ---------------- cooperative CSR build (count -> alloc -> fill) ----------------
__global__ void csr_kernel(const int* __restrict__ dst, const int* __restrict__ srcv,
                           int* __restrict__ counts, int* __restrict__ start,
                           int* __restrict__ rank, int* __restrict__ srclist,
                           int* __restrict__ cursor, int n, int e)
{
    cg::grid_group grid = cg::this_grid();
    int gsz = gridDim.x * blockDim.x;
    int g0 = blockIdx.x * blockDim.x + threadIdx.x;
    int lane = threadIdx.x & 63;

    // phase 1: degree count + per-edge arrival rank
    for (int i = g0; i < e; i += gsz)
        rank[i] = atomicAdd(&counts[dst[i]], 1);

    grid.sync();

    // phase 2: alloc — wave-level inclusive scan + one cursor atomic per wave
    for (int i = g0; i < n + 63; i += gsz) {   // +63: keep full waves active for scan
        int c = (i < n) ? counts[i] : 0;
        int incl = c;
#pragma unroll
        for (int d = 1; d < 64; d <<= 1) {
            int t = __shfl_up(incl, d);
            if (lane >= d) incl += t;
        }
        int waveTot = __shfl(incl, 63);
        int base = 0;
        if (lane == 63) base = atomicAdd(cursor, waveTot);
        base = __shfl(base, 63);
        if (i < n) start[i] = base + incl - c;
    }

    grid.sync();

    // phase 3: fill — atomic-free scatter (position unique per edge)
    for (int i = g0; i < e; i += gsz)
        srclist[start[dst[i]] + rank[i]] = srcv[i];
}

// ---------------- fused bf16 MFMA projection GEMM ----------------
// C[m][o] = sum_k featb[m][k] * Wcat[o][k] + bcat[o],  m<50048(pad), o<1024.
// Block: 512 thr = 8 waves; tile 128m x 256n; wave tile 64x64 (4x4 MFMA).
// 1D grid, XCD-co-located decode: p&7 selects XCD; the 4 ysel blocks of one
// mtile share p&7 -> same XCD -> shared featb A-tile stays in that L2.
// mt = (p&7) + 8*((p>>3)>>2), ysel = (p>>3)&3; pad blocks exit uniformly.
// Swapped-operand MFMA: D[n_local][m_local], m_local=lane&15,
// n_local=(lane>>4)*4+reg. q (ysel=0) and v (ysel=2) written fp8 e4m3 into
// the interleaved qv8 buffer (row pitch 512: q at +0, v at +256); k,skip bf16.
__global__ __launch_bounds__(512) void mfma_gemm(
    const ushort* __restrict__ featb, const ushort* __restrict__ Wcat,
    const float* __restrict__ bcat,
    unsigned char* __restrict__ qv8, ushort* __restrict__ kb,
    ushort* __restrict__ sb, int n, int mtiles)
{
    __shared__ ushort At[128 * 32];  // 8 KB
    __shared__ ushort Bt[256 * 32];  // 16 KB
    int p = blockIdx.x;
    int xcd = p & 7;
    int ii = p >> 3;
    int mt = xcd + 8 * (ii >> 2);
    int ysel = ii & 3;               // 0..3: q,k,v,skip
    if (mt >= mtiles) return;        // uniform pad-block exit
    int tid = threadIdx.x;
    int lane = tid & 63;
    int wv = tid >> 6;               // 0..7
    int mBase = mt * 128;
    int nBlk = ysel * 256;
    int mQuad = (wv & 1) * 64;
    int nQuad = (wv >> 1) * 64;

    floatx4 zero = {0.f, 0.f, 0.f, 0.f};
    floatx4 acc[4][4];               // [m-tile][n-tile]
#pragma unroll
    for (int i = 0; i < 4; ++i)
#pragma unroll
        for (int j = 0; j < 4; ++j) acc[i][j] = zero;

    int rsel = lane & 15;
    int ksel = (lane >> 4) * 8;
    int lrow = lane >> 2;            // 0..15
    int lcol = (lane & 3) * 8;       // ushort offset 0,8,16,24

    for (int k0 = 0; k0 < 256; k0 += 32) {
        {
            int row = 16 * wv + lrow;
            const ushort* gp = featb + (size_t)(mBase + row) * 256 + k0 + lcol;
            __builtin_amdgcn_global_load_lds((gbl_void*)gp, (lds_void*)&At[16 * wv * 32], 16, 0, 0);
        }
#pragma unroll
        for (int r = 0; r < 2; ++r) {
            int row = 32 * wv + 16 * r + lrow;
            const ushort* gp = Wcat + (size_t)(nBlk + row) * 256 + k0 + lcol;
            __builtin_amdgcn_global_load_lds((gbl_void*)gp, (lds_void*)&Bt[(32 * wv + 16 * r) * 32], 16, 0, 0);
        }
        __syncthreads();
        short8 af[4], bf[4];
#pragma unroll
        for (int i = 0; i < 4; ++i)
            af[i] = *(const short8*)&At[(mQuad + 16 * i + rsel) * 32 + ksel];
#pragma unroll
        for (int j = 0; j < 4; ++j)
            bf[j] = *(const short8*)&Bt[(nQuad + 16 * j + rsel) * 32 + ksel];
#pragma unroll
        for (int i = 0; i < 4; ++i)
#pragma unroll
            for (int j = 0; j < 4; ++j)
                acc[i][j] = __builtin_amdgcn_mfma_f32_16x16x32_bf16(bf[j], af[i], acc[i][j], 0, 0, 0);
        __syncthreads();
    }

    int rowq4 = (lane >> 4) * 4;     // n_local base of this lane's 4 cols
    float4 bias[4];
#pragma unroll
    for (int nt = 0; nt < 4; ++nt)
        bias[nt] = *(const float4*)(bcat + nBlk + nQuad + 16 * nt + rowq4);

    if (ysel == 0 || ysel == 2) {            // fp8 outputs (q / v) -> qv8
        unsigned char* outp = qv8 + ((ysel == 0) ? 0 : 256);
#pragma unroll
        for (int mt2 = 0; mt2 < 4; ++mt2) {
            int m = mBase + mQuad + 16 * mt2 + (lane & 15);
            if (m < n) {
                unsigned char* rowp = outp + (size_t)m * 512 + nQuad + rowq4;
#pragma unroll
                for (int nt = 0; nt < 4; ++nt) {
                    int pk = __builtin_amdgcn_cvt_pk_fp8_f32(
                        acc[mt2][nt][0] + bias[nt].x, acc[mt2][nt][1] + bias[nt].y, 0, false);
                    pk = __builtin_amdgcn_cvt_pk_fp8_f32(
                        acc[mt2][nt][2] + bias[nt].z, acc[mt2][nt][3] + bias[nt].w, pk, true);
                    *(int*)(rowp + 16 * nt) = pk;
                }
            }
        }
    } else {                                  // bf16 outputs (k / skip)
        ushort* outp = (ysel == 1) ? kb : sb;
#pragma unroll
        for (int mt2 = 0; mt2 < 4; ++mt2) {
            int m = mBase + mQuad + 16 * mt2 + (lane & 15);
            if (m < n) {
                ushort* rowp = outp + (size_t)m * 256 + nQuad + rowq4;
#pragma unroll
                for (int nt = 0; nt < 4; ++nt) {
                    uint lo = (uint)f2bf(acc[mt2][nt][0] + bias[nt].x)
                            | ((uint)f2bf(acc[mt2][nt][1] + bias[nt].y) << 16);
                    uint hi = (uint)f2bf(acc[mt2][nt][2] + bias[nt].z)
                            | ((uint)f2bf(acc[mt2][nt][3] + bias[nt].w) << 16);
                    *(uint2*)(rowp + 16 * nt) = make_uint2(lo, hi);
                }
            }
        }
    }
}

// ---------------- per-node attention + epilogue ----------------
// One wave per dst node (static). Lane owns 8 consecutive features
// f0=(lane&31)*8; the two 32-lane halves process different edges. 4 chains
// per iteration -> 8 edges / 8 dwordx2 gathers in flight. q and v for one
// edge share one base address (qv8 row, v at +256 imm offset). Logit
// reduce: 3 shfl_xor over the 8-lane head group. No-max softmax
// (shift-invariant; logits tiny). Cross-half combine at end; epilogue
// runs redundantly in both halves, stores split.
__global__ __launch_bounds__(256) void node_kernel(
    const unsigned char* __restrict__ qv8, const ushort* __restrict__ kb,
    const ushort* __restrict__ sbuf,
    const int* __restrict__ srclist, const int* __restrict__ start,
    const int* __restrict__ counts,
    const float* __restrict__ wgs, const float* __restrict__ wgr,
    const float* __restrict__ bg,
    const float* __restrict__ lnw, const float* __restrict__ lnb,
    const float* __restrict__ pa,
    float* __restrict__ out, int n, int E)
{
    int wvi = threadIdx.x >> 6;
    int lane = threadIdx.x & 63;
    int node = blockIdx.x * 4 + wvi;
    if (node >= n) return;

    int l32 = lane & 31;
    int half = lane >> 5;
    int f0 = l32 * 8;                 // 8 consecutive features, head = l32>>3

    short8 kv = *(const short8*)(kb + (size_t)node * 256 + f0);
    float kf[8];
#pragma unroll
    for (int i = 0; i < 8; ++i) kf[i] = bf2f((unsigned short)kv[i]);

    float acc[8];
#pragma unroll
    for (int i = 0; i < 8; ++i) acc[i] = 0.f;
    float denom = 0.f;

    int sidx = start[node], cnt = counts[node];

    for (int base = 0; base < cnt; base += 64) {
        int m = min(64, cnt - base);
        int batch = srclist[min(sidx + base + lane, E - 1)];
        for (int j = 0; j < m; j += 8) {
            int e0 = j + half;        // half 0: j, half 1: j+1
            int e1 = e0 + 2;
            int e2 = e0 + 4;
            int e3 = e0 + 6;
            bool vld0 = e0 < m;
            bool vld1 = e1 < m;
            bool vld2 = e2 < m;
            bool vld3 = e3 < m;
            int s0 = __shfl(batch, vld0 ? e0 : 0);
            int s1 = __shfl(batch, vld1 ? e1 : 0);
            int s2 = __shfl(batch, vld2 ? e2 : 0);
            int s3 = __shfl(batch, vld3 ? e3 : 0);
            const unsigned char* p0 = qv8 + (size_t)s0 * 512 + f0;
            const unsigned char* p1 = qv8 + (size_t)s1 * 512 + f0;
            const unsigned char* p2 = qv8 + (size_t)s2 * 512 + f0;
            const unsigned char* p3 = qv8 + (size_t)s3 * 512 + f0;
            uint2 qw0 = *(const uint2*)p0;
            uint2 qw1 = *(const uint2*)p1;
            uint2 qw2 = *(const uint2*)p2;
            uint2 qw3 = *(const uint2*)p3;
            uint2 vw0 = *(const uint2*)(p0 + 256);
            uint2 vw1 = *(const uint2*)(p1 + 256);
            uint2 vw2 = *(const uint2*)(p2 + 256);
            uint2 vw3 = *(const uint2*)(p3 + 256);

            // ---- logits (4 chains) ----
            floatx2 a0l = __builtin_amdgcn_cvt_pk_f32_fp8(qw0.x, false);
            floatx2 a0h = __builtin_amdgcn_cvt_pk_f32_fp8(qw0.x, true);
            floatx2 a0m = __builtin_amdgcn_cvt_pk_f32_fp8(qw0.y, false);
            floatx2 a0t = __builtin_amdgcn_cvt_pk_f32_fp8(qw0.y, true);
            floatx2 a1l = __builtin_amdgcn_cvt_pk_f32_fp8(qw1.x, false);
            floatx2 a1h = __builtin_amdgcn_cvt_pk_f32_fp8(qw1.x, true);
            floatx2 a1m = __builtin_amdgcn_cvt_pk_f32_fp8(qw1.y, false);
            floatx2 a1t = __builtin_amdgcn_cvt_pk_f32_fp8(qw1.y, true);
            floatx2 a2l = __builtin_amdgcn_cvt_pk_f32_fp8(qw2.x, false);
            floatx2 a2h = __builtin_amdgcn_cvt_pk_f32_fp8(qw2.x, true);
            floatx2 a2m = __builtin_amdgcn_cvt_pk_f32_fp8(qw2.y, false);
            floatx2 a2t = __builtin_amdgcn_cvt_pk_f32_fp8(qw2.y, true);
            floatx2 a3l = __builtin_amdgcn_cvt_pk_f32_fp8(qw3.x, false);
            floatx2 a3h = __builtin_amdgcn_cvt_pk_f32_fp8(qw3.x, true);
            floatx2 a3m = __builtin_amdgcn_cvt_pk_f32_fp8(qw3.y, false);
            floatx2 a3t = __builtin_amdgcn_cvt_pk_f32_fp8(qw3.y, true);

            float p0f = a0l[0]*kf[0]; p0f = fmaf(a0l[1], kf[1], p0f);
            p0f = fmaf(a0h[0], kf[2], p0f); p0f = fmaf(a0h[1], kf[3], p0f);
            p0f = fmaf(a0m[0], kf[4], p0f); p0f = fmaf(a0m[1], kf[5], p0f);
            p0f = fmaf(a0t[0], kf[6], p0f); p0f = fmaf(a0t[1], kf[7], p0f);
            float p1f = a1l[0]*kf[0]; p1f = fmaf(a1l[1], kf[1], p1f);
            p1f = fmaf(a1h[0], kf[2], p1f); p1f = fmaf(a1h[1], kf[3], p1f);
            p1f = fmaf(a1m[0], kf[4], p1f); p1f = fmaf(a1m[1], kf[5], p1f);
            p1f = fmaf(a1t[0], kf[6], p1f); p1f = fmaf(a1t[1], kf[7], p1f);
            float p2f = a2l[0]*kf[0]; p2f = fmaf(a2l[1], kf[1], p2f);
            p2f = fmaf(a2h[0], kf[2], p2f); p2f = fmaf(a2h[1], kf[3], p2f);
            p2f = fmaf(a2m[0], kf[4], p2f); p2f = fmaf(a2m[1], kf[5], p2f);
            p2f = fmaf(a2t[0], kf[6], p2f); p2f = fmaf(a2t[1], kf[7], p2f);
            float p3f = a3l[0]*kf[0]; p3f = fmaf(a3l[1], kf[1], p3f);
            p3f = fmaf(a3h[0], kf[2], p3f); p3f = fmaf(a3h[1], kf[3], p3f);
            p3f = fmaf(a3m[0], kf[4], p3f); p3f = fmaf(a3m[1], kf[5], p3f);
            p3f = fmaf(a3t[0], kf[6], p3f); p3f = fmaf(a3t[1], kf[7], p3f);

            p0f += __shfl_xor(p0f, 1);  p1f += __shfl_xor(p1f, 1);
            p2f += __shfl_xor(p2f, 1);  p3f += __shfl_xor(p3f, 1);
            p0f += __shfl_xor(p0f, 2);  p1f += __shfl_xor(p1f, 2);
            p2f += __shfl_xor(p2f, 2);  p3f += __shfl_xor(p3f, 2);
            p0f += __shfl_xor(p0f, 4);  p1f += __shfl_xor(p1f, 4);
            p2f += __shfl_xor(p2f, 4);  p3f += __shfl_xor(p3f, 4);
            float w0 = vld0 ? __expf(p0f * 0.125f) : 0.f;
            float w1 = vld1 ? __expf(p1f * 0.125f) : 0.f;
            float w2 = vld2 ? __expf(p2f * 0.125f) : 0.f;
            float w3 = vld3 ? __expf(p3f * 0.125f) : 0.f;
            denom += (w0 + w1) + (w2 + w3);

            // ---- weighted V accumulate ----
            floatx2 x0l = __builtin_amdgcn_cvt_pk_f32_fp8(vw0.x, false);
            floatx2 x0h = __builtin_amdgcn_cvt_pk_f32_fp8(vw0.x, true);
            floatx2 x0m = __builtin_amdgcn_cvt_pk_f32_fp8(vw0.y, false);
            floatx2 x0t = __builtin_amdgcn_cvt_pk_f32_fp8(vw0.y, true);
            floatx2 x1l = __builtin_amdgcn_cvt_pk_f32_fp8(vw1.x, false);
            floatx2 x1h = __builtin_amdgcn_cvt_pk_f32_fp8(vw1.x, true);
            floatx2 x1m = __builtin_amdgcn_cvt_pk_f32_fp8(vw1.y, false);
            floatx2 x1t = __builtin_amdgcn_cvt_pk_f32_fp8(vw1.y, true);
            floatx2 x2l = __builtin_amdgcn_cvt_pk_f32_fp8(vw2.x, false);
            floatx2 x2h = __builtin_amdgcn_cvt_pk_f32_fp8(vw2.x, true);
            floatx2 x2m = __builtin_amdgcn_cvt_pk_f32_fp8(vw2.y, false);
            floatx2 x2t = __builtin_amdgcn_cvt_pk_f32_fp8(vw2.y, true);
            floatx2 x3l = __builtin_amdgcn_cvt_pk_f32_fp8(vw3.x, false);
            floatx2 x3h = __builtin_amdgcn_cvt_pk_f32_fp8(vw3.x, true);
            floatx2 x3m = __builtin_amdgcn_cvt_pk_f32_fp8(vw3.y, false);
            floatx2 x3t = __builtin_amdgcn_cvt_pk_f32_fp8(vw3.y, true);

            acc[0] = fmaf(w0, x0l[0], fmaf(w1, x1l[0], fmaf(w2, x2l[0], fmaf(w3, x3l[0], acc[0]))));
            acc[1] = fmaf(w0, x0l[1], fmaf(w1, x1l[1], fmaf(w2, x2l[1], fmaf(w3, x3l[1], acc[1]))));
            acc[2] = fmaf(w0, x0h[0], fmaf(w1, x1h[0], fmaf(w2, x2h[0], fmaf(w3, x3h[0], acc[2]))));
            acc[3] = fmaf(w0, x0h[1], fmaf(w1, x1h[1], fmaf(w2, x2h[1], fmaf(w3, x3h[1], acc[3]))));
            acc[4] = fmaf(w0, x0m[0], fmaf(w1, x1m[0], fmaf(w2, x2m[0], fmaf(w3, x3m[0], acc[4]))));
            acc[5] = fmaf(w0, x0m[1], fmaf(w1, x1m[1], fmaf(w2, x2m[1], fmaf(w3, x3m[1], acc[5]))));
            acc[6] = fmaf(w0, x0t[0], fmaf(w1, x1t[0], fmaf(w2, x2t[0], fmaf(w3, x3t[0], acc[6]))));
            acc[7] = fmaf(w0, x0t[1], fmaf(w1, x1t[1], fmaf(w2, x2t[1], fmaf(w3, x3t[1], acc[7]))));
        }
    }

    // combine the two halves (after this both halves hold identical data)
#pragma unroll
    for (int i = 0; i < 8; ++i) acc[i] += __shfl_xor(acc[i], 32);
    denom += __shfl_xor(denom, 32);
    float inv = (denom > 0.f) ? 1.f / denom : 0.f;
    float r[8];
#pragma unroll
    for (int i = 0; i < 8; ++i) r[i] = acc[i] * inv;

    short8 sv = *(const short8*)(sbuf + (size_t)node * 256 + f0);
    float s[8];
#pragma unroll
    for (int i = 0; i < 8; ++i) s[i] = bf2f((unsigned short)sv[i]);

    // gate: z = wgs.s + wgr.r + bg (weights pre-folded in prep)
    float4 g0 = *(const float4*)(wgs + f0);
    float4 g1 = *(const float4*)(wgs + f0 + 4);
    float4 h0 = *(const float4*)(wgr + f0);
    float4 h1 = *(const float4*)(wgr + f0 + 4);
    float z = g0.x*s[0] + g0.y*s[1] + g0.z*s[2] + g0.w*s[3]
            + g1.x*s[4] + g1.y*s[5] + g1.z*s[6] + g1.w*s[7]
            + h0.x*r[0] + h0.y*r[1] + h0.z*r[2] + h0.w*r[3]
            + h1.x*r[4] + h1.y*r[5] + h1.z*r[6] + h1.w*r[7];
#pragma unroll
    for (int d = 16; d >= 1; d >>= 1) z += __shfl_xor(z, d);   // per-half = full sum
    z += bg[0];
    float g = 1.f / (1.f + __expf(-z));

    float y[8];
#pragma unroll
    for (int i = 0; i < 8; ++i) y[i] = g * s[i] + (1.f - g) * r[i];

    float sum = y[0]+y[1]+y[2]+y[3]+y[4]+y[5]+y[6]+y[7];
#pragma unroll
    for (int d = 16; d >= 1; d >>= 1) sum += __shfl_xor(sum, d);
    float mu = sum * (1.f / 256.f);
    float dv[8];
    float sq = 0.f;
#pragma unroll
    for (int i = 0; i < 8; ++i) { dv[i] = y[i] - mu; sq = fmaf(dv[i], dv[i], sq); }
#pragma unroll
    for (int d = 16; d >= 1; d >>= 1) sq += __shfl_xor(sq, d);
    float rstd = rsqrtf(sq * (1.f / 256.f) + 1e-5f);

    float4 lw0 = *(const float4*)(lnw + f0);
    float4 lw1 = *(const float4*)(lnw + f0 + 4);
    float4 lb0 = *(const float4*)(lnb + f0);
    float4 lb1 = *(const float4*)(lnb + f0 + 4);
    float lwv[8] = {lw0.x, lw0.y, lw0.z, lw0.w, lw1.x, lw1.y, lw1.z, lw1.w};
    float lbv[8] = {lb0.x, lb0.y, lb0.z, lb0.w, lb1.x, lb1.y, lb1.z, lb1.w};
    float ap = pa[0];
    float o[8];
#pragma unroll
    for (int i = 0; i < 8; ++i) {
        float t = dv[i] * rstd * lwv[i] + lbv[i];
        o[i] = (t >= 0.f) ? t : ap * t;
    }

    // halves hold identical o[]; half 0 stores o[0..3], half 1 stores o[4..7]
    float4 stv;
    stv.x = half ? o[4] : o[0];
    stv.y = half ? o[5] : o[1];
    stv.z = half ? o[6] : o[2];
    stv.w = half ? o[7] : o[3];
    *(float4*)(out + (size_t)node * 256 + f0 + 4 * half) = stv;
}

// ---------------- launch ----------------

extern "C" void kernel_launch(void* const* d_in, const int* in_sizes, int n_in,
                              void* d_out, int out_size, void* d_ws, size_t ws_size,
                              hipStream_t stream)
{
    const float* feat = (const float*)d_in[0];
    const int* src    = (const int*)d_in[1];
    const int* dst    = (const int*)d_in[2];
    const float* Wq   = (const float*)d_in[3];
    const float* bq   = (const float*)d_in[4];
    const float* Wk   = (const float*)d_in[5];
    const float* bk   = (const float*)d_in[6];
    const float* Wv   = (const float*)d_in[7];
    const float* bv   = (const float*)d_in[8];
    const float* Wsk  = (const float*)d_in[9];
    const float* bsk  = (const float*)d_in[10];
    const float* Wg   = (const float*)d_in[11];
    const float* bg   = (const float*)d_in[12];
    const float* lnw  = (const float*)d_in[13];
    const float* lnb  = (const float*)d_in[14];
    const float* pa   = (const float*)d_in[15];

    int N = in_sizes[0] / 256;
    int E = in_sizes[1];
    float* out = (float*)d_out;

    int Mtiles = (N + 127) / 128;
    int Npad = Mtiles * 128;

    char* ws = (char*)d_ws;
    size_t off = 0;
    auto alloc = [&](size_t bytes) { char* p = ws + off; off = (off + bytes + 255) & ~(size_t)255; return p; };
    ushort* featb      = (ushort*)alloc((size_t)Npad * 256 * 2);
    ushort* Wcat       = (ushort*)alloc(1024 * 256 * 2);
    float*  bcat       = (float*) alloc(1024 * 4);
    float*  wgs        = (float*) alloc(256 * 4);
    float*  wgr        = (float*) alloc(256 * 4);
    unsigned char* qv8 = (unsigned char*)alloc((size_t)N * 512);
    ushort* kb         = (ushort*)alloc((size_t)N * 256 * 2);
    ushort* sb         = (ushort*)alloc((size_t)N * 256 * 2);
    int* counts        = (int*)alloc((size_t)N * 4);
    int* startv        = (int*)alloc((size_t)N * 4);
    int* rank          = (int*)alloc((size_t)E * 4);
    int* cursor        = (int*)alloc(4);
    int* srclist       = (int*)alloc((size_t)E * 4);

    int totPad = Npad * 256;
    int prepThreads = totPad / 4 + 65536 + 256 + 128 + N;
    prep_kernel<<<(prepThreads + 255) / 256, 256, 0, stream>>>(
        feat, featb, N * 256, totPad, Wq, Wk, Wv, Wsk, bq, bk, bv, bsk, Wg,
        Wcat, bcat, wgs, wgr, counts, cursor, N);

    // cooperative CSR build: count -> sync -> alloc -> sync -> fill
    {
        void* args[] = {(void*)&dst, (void*)&src, (void*)&counts, (void*)&startv,
                        (void*)&rank, (void*)&srclist, (void*)&cursor,
                        (void*)&N, (void*)&E};
        hipLaunchCooperativeKernel((void*)csr_kernel, dim3(1024), dim3(256),
                                   args, 0, stream);
    }

    // XCD-co-located 1D grid: pad mtiles to a multiple of 8 so the decode
    // (xcd = p&7) is bijective; pad blocks exit uniformly in-kernel.
    int Mpad8 = ((Mtiles + 7) / 8) * 8;
    mfma_gemm<<<Mpad8 * 4, 512, 0, stream>>>(featb, Wcat, bcat, qv8, kb, sb, N, Mtiles);

    node_kernel<<<(N + 3) / 4, 256, 0, stream>>>(qv8, kb, sb, srclist, startv, counts,
                                                 wgs, wgr, bg, lnw, lnb, pa, out, N, E);
}

// Round 10
// 316.030 us; speedup vs baseline: 1.6635x; 1.6635x over previous
//
#include <hip/hip_runtime.h>
#include <math.h>

// GraphAttnModel: N=50000, E=800000, F=256, H=4, D=64.
// Pipeline:
//   1) prep: convert feat+weights+biases to bf16 ws copies, fold gate weights
//      (wgs=Wa+Wc, wgr=Wb-Wc), zero CSR counters
//   2) CSR-by-dst build: count (writes per-edge rank via atomic return) /
//      alloc (scan-free wave atomics) / fill (ATOMIC-FREE: pos=start+rank)
//   3) fused bf16 MFMA GEMM (128x256 tile, global_load_lds staging).
//      XCD-co-located grid: the 4 ysel blocks of one mtile map to the SAME
//      XCD (p&7) so the shared featb A-tile is an L2 hit, not 4x L3.
//      q,v outputs stored FP8 e4m3 INTERLEAVED per node (512B row: q|v);
//      k,skip stored bf16.
//   4) node phase: 8192 GRID-STRIDE PERSISTENT waves (no atomics, static
//      stride) — each wave processes ~6 nodes, averaging degree variance.
//      8 feats/lane, two 32-lane halves, 4 chains -> 8 edges / 8 dwordx2
//      gathers in flight. No-max softmax (logits tiny; shift-invariant)
//      + gate + LayerNorm + PReLU, f32 output.

#define NODE_WAVES 8192   // 2048 blocks x 4 waves; must match launch

typedef __attribute__((ext_vector_type(8))) short short8;   // 8 bf16 = 4 VGPRs
typedef __attribute__((ext_vector_type(4))) float floatx4;  // MFMA acc
typedef __attribute__((ext_vector_type(2))) float floatx2;  // fp8 decode pair
typedef __attribute__((address_space(3))) void lds_void;
typedef __attribute__((address_space(1))) const void gbl_void;

__device__ inline unsigned short f2bf(float x) {            // RNE f32->bf16
    unsigned int u = __float_as_uint(x);
    u = (u + 0x7fffu + ((u >> 16) & 1u)) >> 16;
    return (unsigned short)u;
}
__device__ inline float bf2f(unsigned short u) {
    return __uint_as_float(((unsigned int)u) << 16);
}

// ---------------- prep: converts + gate-fold + CSR zero ----------------
__global__ void prep_kernel(const float* __restrict__ f, ushort* __restrict__ fb,
                            int n_elems, int total_pad,
                            const float* __restrict__ Wq, const float* __restrict__ Wk,
                            const float* __restrict__ Wv, const float* __restrict__ Wsk,
                            const float* __restrict__ bq, const float* __restrict__ bk,
                            const float* __restrict__ bv, const float* __restrict__ bsk,
                            const float* __restrict__ Wg,
                            ushort* __restrict__ Wcat, float* __restrict__ bcat,
                            float* __restrict__ wgs, float* __restrict__ wgr,
                            int* __restrict__ counts, int* __restrict__ cursor, int n)
{
    int g = blockIdx.x * blockDim.x + threadIdx.x;
    int featQ = total_pad >> 2;               // feat quads
    if (g < featQ) {
        int i = g * 4;
        float4 v = (i < n_elems) ? *(const float4*)(f + i) : make_float4(0.f, 0.f, 0.f, 0.f);
        ushort4 u;
        u.x = f2bf(v.x); u.y = f2bf(v.y); u.z = f2bf(v.z); u.w = f2bf(v.w);
        *(ushort4*)(fb + i) = u;
        return;
    }
    int g2 = g - featQ;
    if (g2 < 65536) {                         // weights: 262144/4
        int i = g2 * 4;
        int mat = i >> 16;
        int rem = i & 65535;
        const float* W = (mat == 0) ? Wq : (mat == 1) ? Wk : (mat == 2) ? Wv : Wsk;
        float4 v = *(const float4*)(W + rem);
        ushort4 u;
        u.x = f2bf(v.x); u.y = f2bf(v.y); u.z = f2bf(v.z); u.w = f2bf(v.w);
        *(ushort4*)(Wcat + i) = u;
        return;
    }
    int g3 = g2 - 65536;
    if (g3 < 256) {                           // biases: 1024/4
        int o = g3 * 4;
        int mat = o >> 8;
        const float* b = (mat == 0) ? bq : (mat == 1) ? bk : (mat == 2) ? bv : bsk;
        *(float4*)(bcat + o) = *(const float4*)(b + (o & 255));
        return;
    }
    int g4 = g3 - 256;
    if (g4 < 64) {                            // wgs = Wg[0:256] + Wg[512:768]
        int o = g4 * 4;
        float4 a = *(const float4*)(Wg + o);
        float4 c = *(const float4*)(Wg + 512 + o);
        *(float4*)(wgs + o) = make_float4(a.x + c.x, a.y + c.y, a.z + c.z, a.w + c.w);
        return;
    }
    if (g4 < 128) {                           // wgr = Wg[256:512] - Wg[512:768]
        int o = (g4 - 64) * 4;
        float4 b = *(const float4*)(Wg + 256 + o);
        float4 c = *(const float4*)(Wg + 512 + o);
        *(float4*)(wgr + o) = make_float4(b.x - c.x, b.y - c.y, b.z - c.z, b.w - c.w);
        return;
    }
    int g5 = g4 - 128;
    if (g5 < n) counts[g5] = 0;
    if (g5 == 0) *cursor = 0;
}

// ---------------- CSR build ----------------
// count: per-edge arrival rank via atomic return (coalesced 4B write).
__global__ void count_kernel(const int* __restrict__ dst, int* counts,
                             int* __restrict__ rank, int e) {
    int i = blockIdx.x * blockDim.x + threadIdx.x;
    if (i < e) rank[i] = atomicAdd(&counts[dst[i]], 1);
}

__global__ void alloc_kernel(const int* __restrict__ counts, int* start,
                             int* cursor, int n) {
    int i = blockIdx.x * blockDim.x + threadIdx.x;
    int lane = threadIdx.x & 63;
    int c = (i < n) ? counts[i] : 0;
    int incl = c;
#pragma unroll
    for (int d = 1; d < 64; d <<= 1) {
        int t = __shfl_up(incl, d);
        if (lane >= d) incl += t;
    }
    int waveTot = __shfl(incl, 63);
    int base = 0;
    if (lane == 63) base = atomicAdd(cursor, waveTot);
    base = __shfl(base, 63);
    if (i < n) start[i] = base + incl - c;
}

// fill: ATOMIC-FREE scatter — position = start[dst] + rank (unique per edge).
__global__ void fill_kernel(const int* __restrict__ dst, const int* __restrict__ src,
                            const int* __restrict__ start, const int* __restrict__ rank,
                            int* srclist, int e) {
    int i = blockIdx.x * blockDim.x + threadIdx.x;
    if (i < e) srclist[start[dst[i]] + rank[i]] = src[i];
}

// ---------------- fused bf16 MFMA projection GEMM ----------------
// C[m][o] = sum_k featb[m][k] * Wcat[o][k] + bcat[o],  m<50048(pad), o<1024.
// Block: 512 thr = 8 waves; tile 128m x 256n; wave tile 64x64 (4x4 MFMA).
// 1D grid, XCD-co-located decode: p&7 selects XCD; the 4 ysel blocks of one
// mtile share p&7 -> same XCD -> shared featb A-tile stays in that L2.
// mt = (p&7) + 8*((p>>3)>>2), ysel = (p>>3)&3; pad blocks exit uniformly.
// Swapped-operand MFMA: D[n_local][m_local], m_local=lane&15,
// n_local=(lane>>4)*4+reg. q (ysel=0) and v (ysel=2) written fp8 e4m3 into
// the interleaved qv8 buffer (row pitch 512: q at +0, v at +256); k,skip bf16.
__global__ __launch_bounds__(512) void mfma_gemm(
    const ushort* __restrict__ featb, const ushort* __restrict__ Wcat,
    const float* __restrict__ bcat,
    unsigned char* __restrict__ qv8, ushort* __restrict__ kb,
    ushort* __restrict__ sb, int n, int mtiles)
{
    __shared__ ushort At[128 * 32];  // 8 KB
    __shared__ ushort Bt[256 * 32];  // 16 KB
    int p = blockIdx.x;
    int xcd = p & 7;
    int ii = p >> 3;
    int mt = xcd + 8 * (ii >> 2);
    int ysel = ii & 3;               // 0..3: q,k,v,skip
    if (mt >= mtiles) return;        // uniform pad-block exit
    int tid = threadIdx.x;
    int lane = tid & 63;
    int wv = tid >> 6;               // 0..7
    int mBase = mt * 128;
    int nBlk = ysel * 256;
    int mQuad = (wv & 1) * 64;
    int nQuad = (wv >> 1) * 64;

    floatx4 zero = {0.f, 0.f, 0.f, 0.f};
    floatx4 acc[4][4];               // [m-tile][n-tile]
#pragma unroll
    for (int i = 0; i < 4; ++i)
#pragma unroll
        for (int j = 0; j < 4; ++j) acc[i][j] = zero;

    int rsel = lane & 15;
    int ksel = (lane >> 4) * 8;
    int lrow = lane >> 2;            // 0..15
    int lcol = (lane & 3) * 8;       // ushort offset 0,8,16,24

    for (int k0 = 0; k0 < 256; k0 += 32) {
        {
            int row = 16 * wv + lrow;
            const ushort* gp = featb + (size_t)(mBase + row) * 256 + k0 + lcol;
            __builtin_amdgcn_global_load_lds((gbl_void*)gp, (lds_void*)&At[16 * wv * 32], 16, 0, 0);
        }
#pragma unroll
        for (int r = 0; r < 2; ++r) {
            int row = 32 * wv + 16 * r + lrow;
            const ushort* gp = Wcat + (size_t)(nBlk + row) * 256 + k0 + lcol;
            __builtin_amdgcn_global_load_lds((gbl_void*)gp, (lds_void*)&Bt[(32 * wv + 16 * r) * 32], 16, 0, 0);
        }
        __syncthreads();
        short8 af[4], bf[4];
#pragma unroll
        for (int i = 0; i < 4; ++i)
            af[i] = *(const short8*)&At[(mQuad + 16 * i + rsel) * 32 + ksel];
#pragma unroll
        for (int j = 0; j < 4; ++j)
            bf[j] = *(const short8*)&Bt[(nQuad + 16 * j + rsel) * 32 + ksel];
#pragma unroll
        for (int i = 0; i < 4; ++i)
#pragma unroll
            for (int j = 0; j < 4; ++j)
                acc[i][j] = __builtin_amdgcn_mfma_f32_16x16x32_bf16(bf[j], af[i], acc[i][j], 0, 0, 0);
        __syncthreads();
    }

    int rowq4 = (lane >> 4) * 4;     // n_local base of this lane's 4 cols
    float4 bias[4];
#pragma unroll
    for (int nt = 0; nt < 4; ++nt)
        bias[nt] = *(const float4*)(bcat + nBlk + nQuad + 16 * nt + rowq4);

    if (ysel == 0 || ysel == 2) {            // fp8 outputs (q / v) -> qv8
        unsigned char* outp = qv8 + ((ysel == 0) ? 0 : 256);
#pragma unroll
        for (int mt2 = 0; mt2 < 4; ++mt2) {
            int m = mBase + mQuad + 16 * mt2 + (lane & 15);
            if (m < n) {
                unsigned char* rowp = outp + (size_t)m * 512 + nQuad + rowq4;
#pragma unroll
                for (int nt = 0; nt < 4; ++nt) {
                    int pk = __builtin_amdgcn_cvt_pk_fp8_f32(
                        acc[mt2][nt][0] + bias[nt].x, acc[mt2][nt][1] + bias[nt].y, 0, false);
                    pk = __builtin_amdgcn_cvt_pk_fp8_f32(
                        acc[mt2][nt][2] + bias[nt].z, acc[mt2][nt][3] + bias[nt].w, pk, true);
                    *(int*)(rowp + 16 * nt) = pk;
                }
            }
        }
    } else {                                  // bf16 outputs (k / skip)
        ushort* outp = (ysel == 1) ? kb : sb;
#pragma unroll
        for (int mt2 = 0; mt2 < 4; ++mt2) {
            int m = mBase + mQuad + 16 * mt2 + (lane & 15);
            if (m < n) {
                ushort* rowp = outp + (size_t)m * 256 + nQuad + rowq4;
#pragma unroll
                for (int nt = 0; nt < 4; ++nt) {
                    uint lo = (uint)f2bf(acc[mt2][nt][0] + bias[nt].x)
                            | ((uint)f2bf(acc[mt2][nt][1] + bias[nt].y) << 16);
                    uint hi = (uint)f2bf(acc[mt2][nt][2] + bias[nt].z)
                            | ((uint)f2bf(acc[mt2][nt][3] + bias[nt].w) << 16);
                    *(uint2*)(rowp + 16 * nt) = make_uint2(lo, hi);
                }
            }
        }
    }
}

// ---------------- per-node attention + epilogue (grid-stride persistent) ----------------
// 8192 waves; wave w processes nodes w, w+8192, w+16384, ... (~6 nodes) —
// static stride, NO atomics (round-5's ticket hotline lesson). Averaging
// ~6 random degrees per wave cuts block-makespan variance vs 1 node/wave.
// Lane owns 8 consecutive features f0=(lane&31)*8; two 32-lane halves
// process different edges, 4 chains -> 8 edges / 8 dwordx2 gathers in
// flight. q and v share one base address (qv8 row, v at +256). Logit
// reduce: 3 shfl_xor over the 8-lane head group. No-max softmax
// (shift-invariant; logits tiny). Cross-half combine; epilogue redundant
// in both halves, stores split.
__global__ __launch_bounds__(256) void node_kernel(
    const unsigned char* __restrict__ qv8, const ushort* __restrict__ kb,
    const ushort* __restrict__ sbuf,
    const int* __restrict__ srclist, const int* __restrict__ start,
    const int* __restrict__ counts,
    const float* __restrict__ wgs, const float* __restrict__ wgr,
    const float* __restrict__ bg,
    const float* __restrict__ lnw, const float* __restrict__ lnb,
    const float* __restrict__ pa,
    float* __restrict__ out, int n, int E)
{
    int wvi = threadIdx.x >> 6;
    int lane = threadIdx.x & 63;
    int l32 = lane & 31;
    int half = lane >> 5;
    int f0 = l32 * 8;                 // 8 consecutive features, head = l32>>3

    for (int node = blockIdx.x * 4 + wvi; node < n; node += NODE_WAVES) {
        short8 kv = *(const short8*)(kb + (size_t)node * 256 + f0);
        float kf[8];
#pragma unroll
        for (int i = 0; i < 8; ++i) kf[i] = bf2f((unsigned short)kv[i]);

        float acc[8];
#pragma unroll
        for (int i = 0; i < 8; ++i) acc[i] = 0.f;
        float denom = 0.f;

        int sidx = start[node], cnt = counts[node];

        for (int base = 0; base < cnt; base += 64) {
            int m = min(64, cnt - base);
            int batch = srclist[min(sidx + base + lane, E - 1)];
            for (int j = 0; j < m; j += 8) {
                int e0 = j + half;        // half 0: j, half 1: j+1
                int e1 = e0 + 2;
                int e2 = e0 + 4;
                int e3 = e0 + 6;
                bool vld0 = e0 < m;
                bool vld1 = e1 < m;
                bool vld2 = e2 < m;
                bool vld3 = e3 < m;
                int s0 = __shfl(batch, vld0 ? e0 : 0);
                int s1 = __shfl(batch, vld1 ? e1 : 0);
                int s2 = __shfl(batch, vld2 ? e2 : 0);
                int s3 = __shfl(batch, vld3 ? e3 : 0);
                const unsigned char* p0 = qv8 + (size_t)s0 * 512 + f0;
                const unsigned char* p1 = qv8 + (size_t)s1 * 512 + f0;
                const unsigned char* p2 = qv8 + (size_t)s2 * 512 + f0;
                const unsigned char* p3 = qv8 + (size_t)s3 * 512 + f0;
                uint2 qw0 = *(const uint2*)p0;
                uint2 qw1 = *(const uint2*)p1;
                uint2 qw2 = *(const uint2*)p2;
                uint2 qw3 = *(const uint2*)p3;
                uint2 vw0 = *(const uint2*)(p0 + 256);
                uint2 vw1 = *(const uint2*)(p1 + 256);
                uint2 vw2 = *(const uint2*)(p2 + 256);
                uint2 vw3 = *(const uint2*)(p3 + 256);

                // ---- logits (4 chains) ----
                floatx2 a0l = __builtin_amdgcn_cvt_pk_f32_fp8(qw0.x, false);
                floatx2 a0h = __builtin_amdgcn_cvt_pk_f32_fp8(qw0.x, true);
                floatx2 a0m = __builtin_amdgcn_cvt_pk_f32_fp8(qw0.y, false);
                floatx2 a0t = __builtin_amdgcn_cvt_pk_f32_fp8(qw0.y, true);
                floatx2 a1l = __builtin_amdgcn_cvt_pk_f32_fp8(qw1.x, false);
                floatx2 a1h = __builtin_amdgcn_cvt_pk_f32_fp8(qw1.x, true);
                floatx2 a1m = __builtin_amdgcn_cvt_pk_f32_fp8(qw1.y, false);
                floatx2 a1t = __builtin_amdgcn_cvt_pk_f32_fp8(qw1.y, true);
                floatx2 a2l = __builtin_amdgcn_cvt_pk_f32_fp8(qw2.x, false);
                floatx2 a2h = __builtin_amdgcn_cvt_pk_f32_fp8(qw2.x, true);
                floatx2 a2m = __builtin_amdgcn_cvt_pk_f32_fp8(qw2.y, false);
                floatx2 a2t = __builtin_amdgcn_cvt_pk_f32_fp8(qw2.y, true);
                floatx2 a3l = __builtin_amdgcn_cvt_pk_f32_fp8(qw3.x, false);
                floatx2 a3h = __builtin_amdgcn_cvt_pk_f32_fp8(qw3.x, true);
                floatx2 a3m = __builtin_amdgcn_cvt_pk_f32_fp8(qw3.y, false);
                floatx2 a3t = __builtin_amdgcn_cvt_pk_f32_fp8(qw3.y, true);

                float p0f = a0l[0]*kf[0]; p0f = fmaf(a0l[1], kf[1], p0f);
                p0f = fmaf(a0h[0], kf[2], p0f); p0f = fmaf(a0h[1], kf[3], p0f);
                p0f = fmaf(a0m[0], kf[4], p0f); p0f = fmaf(a0m[1], kf[5], p0f);
                p0f = fmaf(a0t[0], kf[6], p0f); p0f = fmaf(a0t[1], kf[7], p0f);
                float p1f = a1l[0]*kf[0]; p1f = fmaf(a1l[1], kf[1], p1f);
                p1f = fmaf(a1h[0], kf[2], p1f); p1f = fmaf(a1h[1], kf[3], p1f);
                p1f = fmaf(a1m[0], kf[4], p1f); p1f = fmaf(a1m[1], kf[5], p1f);
                p1f = fmaf(a1t[0], kf[6], p1f); p1f = fmaf(a1t[1], kf[7], p1f);
                float p2f = a2l[0]*kf[0]; p2f = fmaf(a2l[1], kf[1], p2f);
                p2f = fmaf(a2h[0], kf[2], p2f); p2f = fmaf(a2h[1], kf[3], p2f);
                p2f = fmaf(a2m[0], kf[4], p2f); p2f = fmaf(a2m[1], kf[5], p2f);
                p2f = fmaf(a2t[0], kf[6], p2f); p2f = fmaf(a2t[1], kf[7], p2f);
                float p3f = a3l[0]*kf[0]; p3f = fmaf(a3l[1], kf[1], p3f);
                p3f = fmaf(a3h[0], kf[2], p3f); p3f = fmaf(a3h[1], kf[3], p3f);
                p3f = fmaf(a3m[0], kf[4], p3f); p3f = fmaf(a3m[1], kf[5], p3f);
                p3f = fmaf(a3t[0], kf[6], p3f); p3f = fmaf(a3t[1], kf[7], p3f);

                p0f += __shfl_xor(p0f, 1);  p1f += __shfl_xor(p1f, 1);
                p2f += __shfl_xor(p2f, 1);  p3f += __shfl_xor(p3f, 1);
                p0f += __shfl_xor(p0f, 2);  p1f += __shfl_xor(p1f, 2);
                p2f += __shfl_xor(p2f, 2);  p3f += __shfl_xor(p3f, 2);
                p0f += __shfl_xor(p0f, 4);  p1f += __shfl_xor(p1f, 4);
                p2f += __shfl_xor(p2f, 4);  p3f += __shfl_xor(p3f, 4);
                float w0 = vld0 ? __expf(p0f * 0.125f) : 0.f;
                float w1 = vld1 ? __expf(p1f * 0.125f) : 0.f;
                float w2 = vld2 ? __expf(p2f * 0.125f) : 0.f;
                float w3 = vld3 ? __expf(p3f * 0.125f) : 0.f;
                denom += (w0 + w1) + (w2 + w3);

                // ---- weighted V accumulate ----
                floatx2 x0l = __builtin_amdgcn_cvt_pk_f32_fp8(vw0.x, false);
                floatx2 x0h = __builtin_amdgcn_cvt_pk_f32_fp8(vw0.x, true);
                floatx2 x0m = __builtin_amdgcn_cvt_pk_f32_fp8(vw0.y, false);
                floatx2 x0t = __builtin_amdgcn_cvt_pk_f32_fp8(vw0.y, true);
                floatx2 x1l = __builtin_amdgcn_cvt_pk_f32_fp8(vw1.x, false);
                floatx2 x1h = __builtin_amdgcn_cvt_pk_f32_fp8(vw1.x, true);
                floatx2 x1m = __builtin_amdgcn_cvt_pk_f32_fp8(vw1.y, false);
                floatx2 x1t = __builtin_amdgcn_cvt_pk_f32_fp8(vw1.y, true);
                floatx2 x2l = __builtin_amdgcn_cvt_pk_f32_fp8(vw2.x, false);
                floatx2 x2h = __builtin_amdgcn_cvt_pk_f32_fp8(vw2.x, true);
                floatx2 x2m = __builtin_amdgcn_cvt_pk_f32_fp8(vw2.y, false);
                floatx2 x2t = __builtin_amdgcn_cvt_pk_f32_fp8(vw2.y, true);
                floatx2 x3l = __builtin_amdgcn_cvt_pk_f32_fp8(vw3.x, false);
                floatx2 x3h = __builtin_amdgcn_cvt_pk_f32_fp8(vw3.x, true);
                floatx2 x3m = __builtin_amdgcn_cvt_pk_f32_fp8(vw3.y, false);
                floatx2 x3t = __builtin_amdgcn_cvt_pk_f32_fp8(vw3.y, true);

                acc[0] = fmaf(w0, x0l[0], fmaf(w1, x1l[0], fmaf(w2, x2l[0], fmaf(w3, x3l[0], acc[0]))));
                acc[1] = fmaf(w0, x0l[1], fmaf(w1, x1l[1], fmaf(w2, x2l[1], fmaf(w3, x3l[1], acc[1]))));
                acc[2] = fmaf(w0, x0h[0], fmaf(w1, x1h[0], fmaf(w2, x2h[0], fmaf(w3, x3h[0], acc[2]))));
                acc[3] = fmaf(w0, x0h[1], fmaf(w1, x1h[1], fmaf(w2, x2h[1], fmaf(w3, x3h[1], acc[3]))));
                acc[4] = fmaf(w0, x0m[0], fmaf(w1, x1m[0], fmaf(w2, x2m[0], fmaf(w3, x3m[0], acc[4]))));
                acc[5] = fmaf(w0, x0m[1], fmaf(w1, x1m[1], fmaf(w2, x2m[1], fmaf(w3, x3m[1], acc[5]))));
                acc[6] = fmaf(w0, x0t[0], fmaf(w1, x1t[0], fmaf(w2, x2t[0], fmaf(w3, x3t[0], acc[6]))));
                acc[7] = fmaf(w0, x0t[1], fmaf(w1, x1t[1], fmaf(w2, x2t[1], fmaf(w3, x3t[1], acc[7]))));
            }
        }

        // combine the two halves (after this both halves hold identical data)
#pragma unroll
        for (int i = 0; i < 8; ++i) acc[i] += __shfl_xor(acc[i], 32);
        denom += __shfl_xor(denom, 32);
        float inv = (denom > 0.f) ? 1.f / denom : 0.f;
        float r[8];
#pragma unroll
        for (int i = 0; i < 8; ++i) r[i] = acc[i] * inv;

        short8 sv = *(const short8*)(sbuf + (size_t)node * 256 + f0);
        float s[8];
#pragma unroll
        for (int i = 0; i < 8; ++i) s[i] = bf2f((unsigned short)sv[i]);

        // gate: z = wgs.s + wgr.r + bg (weights pre-folded in prep)
        float4 g0 = *(const float4*)(wgs + f0);
        float4 g1 = *(const float4*)(wgs + f0 + 4);
        float4 h0 = *(const float4*)(wgr + f0);
        float4 h1 = *(const float4*)(wgr + f0 + 4);
        float z = g0.x*s[0] + g0.y*s[1] + g0.z*s[2] + g0.w*s[3]
                + g1.x*s[4] + g1.y*s[5] + g1.z*s[6] + g1.w*s[7]
                + h0.x*r[0] + h0.y*r[1] + h0.z*r[2] + h0.w*r[3]
                + h1.x*r[4] + h1.y*r[5] + h1.z*r[6] + h1.w*r[7];
#pragma unroll
        for (int d = 16; d >= 1; d >>= 1) z += __shfl_xor(z, d);   // per-half = full sum
        z += bg[0];
        float g = 1.f / (1.f + __expf(-z));

        float y[8];
#pragma unroll
        for (int i = 0; i < 8; ++i) y[i] = g * s[i] + (1.f - g) * r[i];

        float sum = y[0]+y[1]+y[2]+y[3]+y[4]+y[5]+y[6]+y[7];
#pragma unroll
        for (int d = 16; d >= 1; d >>= 1) sum += __shfl_xor(sum, d);
        float mu = sum * (1.f / 256.f);
        float dv[8];
        float sq = 0.f;
#pragma unroll
        for (int i = 0; i < 8; ++i) { dv[i] = y[i] - mu; sq = fmaf(dv[i], dv[i], sq); }
#pragma unroll
        for (int d = 16; d >= 1; d >>= 1) sq += __shfl_xor(sq, d);
        float rstd = rsqrtf(sq * (1.f / 256.f) + 1e-5f);

        float4 lw0 = *(const float4*)(lnw + f0);
        float4 lw1 = *(const float4*)(lnw + f0 + 4);
        float4 lb0 = *(const float4*)(lnb + f0);
        float4 lb1 = *(const float4*)(lnb + f0 + 4);
        float lwv[8] = {lw0.x, lw0.y, lw0.z, lw0.w, lw1.x, lw1.y, lw1.z, lw1.w};
        float lbv[8] = {lb0.x, lb0.y, lb0.z, lb0.w, lb1.x, lb1.y, lb1.z, lb1.w};
        float ap = pa[0];
        float o[8];
#pragma unroll
        for (int i = 0; i < 8; ++i) {
            float t = dv[i] * rstd * lwv[i] + lbv[i];
            o[i] = (t >= 0.f) ? t : ap * t;
        }

        // halves hold identical o[]; half 0 stores o[0..3], half 1 stores o[4..7]
        float4 stv;
        stv.x = half ? o[4] : o[0];
        stv.y = half ? o[5] : o[1];
        stv.z = half ? o[6] : o[2];
        stv.w = half ? o[7] : o[3];
        *(float4*)(out + (size_t)node * 256 + f0 + 4 * half) = stv;
    }
}

// ---------------- launch ----------------

extern "C" void kernel_launch(void* const* d_in, const int* in_sizes, int n_in,
                              void* d_out, int out_size, void* d_ws, size_t ws_size,
                              hipStream_t stream)
{
    const float* feat = (const float*)d_in[0];
    const int* src    = (const int*)d_in[1];
    const int* dst    = (const int*)d_in[2];
    const float* Wq   = (const float*)d_in[3];
    const float* bq   = (const float*)d_in[4];
    const float* Wk   = (const float*)d_in[5];
    const float* bk   = (const float*)d_in[6];
    const float* Wv   = (const float*)d_in[7];
    const float* bv   = (const float*)d_in[8];
    const float* Wsk  = (const float*)d_in[9];
    const float* bsk  = (const float*)d_in[10];
    const float* Wg   = (const float*)d_in[11];
    const float* bg   = (const float*)d_in[12];
    const float* lnw  = (const float*)d_in[13];
    const float* lnb  = (const float*)d_in[14];
    const float* pa   = (const float*)d_in[15];

    int N = in_sizes[0] / 256;
    int E = in_sizes[1];
    float* out = (float*)d_out;

    int Mtiles = (N + 127) / 128;
    int Npad = Mtiles * 128;

    char* ws = (char*)d_ws;
    size_t off = 0;
    auto alloc = [&](size_t bytes) { char* p = ws + off; off = (off + bytes + 255) & ~(size_t)255; return p; };
    ushort* featb      = (ushort*)alloc((size_t)Npad * 256 * 2);
    ushort* Wcat       = (ushort*)alloc(1024 * 256 * 2);
    float*  bcat       = (float*) alloc(1024 * 4);
    float*  wgs        = (float*) alloc(256 * 4);
    float*  wgr        = (float*) alloc(256 * 4);
    unsigned char* qv8 = (unsigned char*)alloc((size_t)N * 512);
    ushort* kb         = (ushort*)alloc((size_t)N * 256 * 2);
    ushort* sb         = (ushort*)alloc((size_t)N * 256 * 2);
    int* counts        = (int*)alloc((size_t)N * 4);
    int* startv        = (int*)alloc((size_t)N * 4);
    int* rank          = (int*)alloc((size_t)E * 4);
    int* cursor        = (int*)alloc(4);
    int* srclist       = (int*)alloc((size_t)E * 4);

    int totPad = Npad * 256;
    int prepThreads = totPad / 4 + 65536 + 256 + 128 + N;
    prep_kernel<<<(prepThreads + 255) / 256, 256, 0, stream>>>(
        feat, featb, N * 256, totPad, Wq, Wk, Wv, Wsk, bq, bk, bv, bsk, Wg,
        Wcat, bcat, wgs, wgr, counts, cursor, N);

    count_kernel<<<(E + 255) / 256, 256, 0, stream>>>(dst, counts, rank, E);
    alloc_kernel<<<(N + 255) / 256, 256, 0, stream>>>(counts, startv, cursor, N);
    fill_kernel<<<(E + 255) / 256, 256, 0, stream>>>(dst, src, startv, rank, srclist, E);

    // XCD-co-located 1D grid: pad mtiles to a multiple of 8 so the decode
    // (xcd = p&7) is bijective; pad blocks exit uniformly in-kernel.
    int Mpad8 = ((Mtiles + 7) / 8) * 8;
    mfma_gemm<<<Mpad8 * 4, 512, 0, stream>>>(featb, Wcat, bcat, qv8, kb, sb, N, Mtiles);

    node_kernel<<<NODE_WAVES / 4, 256, 0, stream>>>(qv8, kb, sb, srclist, startv, counts,
                                                    wgs, wgr, bg, lnw, lnb, pa, out, N, E);
}